// Round 2
// baseline (898.905 us; speedup 1.0000x reference)
//
#include <hip/hip_runtime.h>
#include <hip/hip_bf16.h>
#include <math.h>

#define N 1026
#define T 8
#define H 64
#define F_IN 5
#define E 1026
#define NNZ 200000
#define TM 7
#define NG 9
#define SE 1056
#define NW (SE/4)
#define GSZ (N*SE)

#define OFF_PRICE   0
#define OFF_WIH     41040
#define OFF_WHH     42000
#define OFF_BIH     54288
#define OFF_BHH     54480
#define OFF_WIN     54672
#define OFF_WOUT    58768
#define OFF_AE      66960
#define OFF_AB      67986
#define OFF_TH1     69012
#define OFF_B1      73108
#define OFF_TH2     73172
#define OFF_B2      77268
#define OFF_W1      77332
#define OFF_W2      77780
#define OFF_APAR    78228
#define OFF_WL      78235
#define OFF_BL      78363
#define TOT_CVT     78364
#define CVT_PAD     78368

typedef unsigned int u32;

__device__ __forceinline__ float leakyf(float x){ return x >= 0.f ? x : 0.2f*x; }
__device__ __forceinline__ float bfbits2f(unsigned short u){
  union { unsigned int i; float f; } c; c.i = ((unsigned int)u) << 16; return c.f;
}

__global__ __launch_bounds__(64) void k_detect(const unsigned short* __restrict__ w,
                                               int* __restrict__ flag){
  int tid = threadIdx.x;
  int big = 0;
  for (int k = tid; k < 960; k += 64){
    float a = fabsf(bfbits2f(w[k]));
    if (!(a < 1e3f)) big = 1;
  }
  unsigned long long any = __ballot(big != 0);
  if (tid == 0) *flag = (any != 0ull) ? 1 : 0;
}

struct CvtPtrs { const void* p[18]; };

__global__ __launch_bounds__(256) void k_cvt(const int* __restrict__ flag,
                                             CvtPtrs ps, float* __restrict__ dst){
  const int offs[19] = {OFF_PRICE, OFF_WIH, OFF_WHH, OFF_BIH, OFF_BHH, OFF_WIN,
                        OFF_WOUT, OFF_AE, OFF_AB, OFF_TH1, OFF_B1, OFF_TH2,
                        OFF_B2, OFF_W1, OFF_W2, OFF_APAR, OFF_WL, OFF_BL, TOT_CVT};
  int i = blockIdx.x*256 + threadIdx.x;
  if (i >= TOT_CVT) return;
  int t = 0;
  #pragma unroll
  for (int k = 1; k < 18; k++) if (i >= offs[k]) t = k;
  int j = i - offs[t];
  float v;
  if (*flag) v = ((const float*)ps.p[t])[j];
  else       v = bfbits2f(((const unsigned short*)ps.p[t])[j]);
  dst[i] = v;
}

__global__ __launch_bounds__(256) void k_build(const int* __restrict__ hypT,
                                               const int* __restrict__ hyp,
                                               u32* __restrict__ cHm,
                                               u32* __restrict__ cHmT){
  int g = blockIdx.y;
  int i = blockIdx.x*256 + threadIdx.x;
  if (i >= NNZ) return;
  const int* np_; const int* ep_;
  if (g < 8){ np_ = hypT + (size_t)g*2*NNZ; ep_ = np_ + NNZ; }
  else      { np_ = hyp;                    ep_ = hyp + NNZ; }
  int nd = np_[i], ed = ep_[i];
  u32 i1 = (u32)g*GSZ + (u32)nd*SE + (u32)ed;
  atomicAdd(cHm  + (i1>>2), 1u << ((i1&3)*8));
  u32 i2 = (u32)g*GSZ + (u32)ed*SE + (u32)nd;
  atomicAdd(cHmT + (i2>>2), 1u << ((i2&3)*8));
}

__global__ __launch_bounds__(64) void k_deg(const u32* __restrict__ cHm,
                                            const u32* __restrict__ cHmT,
                                            float* __restrict__ Dinv,
                                            float* __restrict__ Binv){
  int r = blockIdx.x, g = blockIdx.y, which = blockIdx.z;
  const u32* base = (which==0 ? cHm : cHmT) + ((size_t)g*GSZ + (size_t)r*SE)/4;
  int tid = threadIdx.x;
  u32 s = 0;
  for (int k = tid; k < NW; k += 64){
    u32 w = base[k];
    s += (w & 0xFFu) + ((w>>8)&0xFFu) + ((w>>16)&0xFFu) + ((w>>24)&0xFFu);
  }
  for (int off = 32; off; off >>= 1) s += __shfl_down(s, off);
  if (tid == 0){
    float v = s ? 1.f/(float)s : 0.f;
    (which==0 ? Dinv : Binv)[g*N + r] = v;
  }
}

__global__ __launch_bounds__(64) void k_gru(const float* __restrict__ price,
                                            const float* __restrict__ Wih,
                                            const float* __restrict__ Whh,
                                            const float* __restrict__ bih,
                                            const float* __restrict__ bhh,
                                            float* __restrict__ ctx,
                                            float* __restrict__ last){
  __shared__ float sWhh[192*64];
  __shared__ float sWih[192*F_IN];
  __shared__ float sbih[192], sbhh[192];
  __shared__ float sh[64];
  __shared__ float sx[T*F_IN];
  int n = blockIdx.x, tid = threadIdx.x;
  for (int k = tid; k < 192*64;   k += 64) sWhh[k] = Whh[k];
  for (int k = tid; k < 192*F_IN; k += 64) sWih[k] = Wih[k];
  for (int k = tid; k < 192;      k += 64){ sbih[k] = bih[k]; sbhh[k] = bhh[k]; }
  for (int k = tid; k < T*F_IN;   k += 64) sx[k] = price[(size_t)n*T*F_IN + k];
  sh[tid] = 0.f;
  __syncthreads();
  for (int t = 0; t < T; t++){
    float ir = sbih[tid], iz = sbih[64+tid], inn = sbih[128+tid];
    for (int d = 0; d < F_IN; d++){
      float x = sx[t*F_IN + d];
      ir  += x * sWih[tid*F_IN + d];
      iz  += x * sWih[(64+tid)*F_IN + d];
      inn += x * sWih[(128+tid)*F_IN + d];
    }
    float hr = sbhh[tid], hz = sbhh[64+tid], hn = sbhh[128+tid];
    for (int d = 0; d < 64; d++){
      float hv = sh[d];
      hr += hv * sWhh[tid*64 + d];
      hz += hv * sWhh[(64+tid)*64 + d];
      hn += hv * sWhh[(128+tid)*64 + d];
    }
    float r  = 1.f/(1.f + expf(-(ir+hr)));
    float z  = 1.f/(1.f + expf(-(iz+hz)));
    float nn = tanhf(inn + r*hn);
    float hnew = (1.f - z)*nn + z*sh[tid];
    __syncthreads();
    sh[tid] = hnew;
    ctx[((size_t)n*T + t)*H + tid] = hnew;
    __syncthreads();
  }
  last[(size_t)n*H + tid] = sh[tid];
}

__global__ __launch_bounds__(64) void k_attn(const float* __restrict__ ctx,
                                             const float* __restrict__ last,
                                             const float* __restrict__ Win,
                                             const float* __restrict__ Wout,
                                             const float* __restrict__ ae,
                                             const float* __restrict__ ab,
                                             float* __restrict__ outp){
  __shared__ float sWin[64*64];
  __shared__ float sWout[128*64];
  __shared__ float sc[T*64];
  __shared__ float sl[64];
  __shared__ float sq[64];
  __shared__ float ss[T];
  __shared__ float sco[128];
  int n = blockIdx.x, tid = threadIdx.x;
  for (int k = tid; k < 64*64;  k += 64) sWin[k]  = Win[k];
  for (int k = tid; k < 128*64; k += 64) sWout[k] = Wout[k];
  for (int k = tid; k < T*64;   k += 64) sc[k] = ctx[(size_t)n*T*H + k];
  sl[tid] = last[(size_t)n*H + tid];
  __syncthreads();
  float q = 0.f;
  for (int d = 0; d < 64; d++) q += sl[d]*sWin[d*64 + tid];
  sq[tid] = q;
  __syncthreads();
  if (tid < T){
    float s = 0.f;
    for (int d = 0; d < 64; d++) s += sq[d]*sc[tid*64 + d];
    ss[tid] = s;
  }
  __syncthreads();
  float m = ss[0];
  for (int t = 1; t < T; t++) m = fmaxf(m, ss[t]);
  float wv[T]; float den = 0.f;
  for (int t = 0; t < T; t++){ wv[t] = expf(ss[t]-m); den += wv[t]; }
  float aen = ae[n], abn = ab[n];
  float mixs = 0.f;
  for (int t = 0; t < T; t++){
    float wt = wv[t]/den;
    float mx = wt * sc[t*64 + tid];
    float bt = expf(-abn * (float)(T-1-t));
    mixs += fmaxf(aen*mx*bt, 0.f) + mx;
  }
  sco[tid] = mixs; sco[64+tid] = q;
  __syncthreads();
  float o = 0.f;
  for (int k = 0; k < 128; k++) o += sco[k]*sWout[k*64 + tid];
  outp[(size_t)n*H + tid] = tanhf(o);
}

__global__ __launch_bounds__(256) void k_xtheta(const float* __restrict__ x,
                                                const float* __restrict__ theta,
                                                float* __restrict__ xt, int rows){
  __shared__ float sth[64*64];
  __shared__ float sx[4][64];
  int tid = threadIdx.x;
  for (int k = tid; k < 4096; k += 256) sth[k] = theta[k];
  int w = tid >> 6, f = tid & 63;
  int r = blockIdx.x*4 + w;
  if (r < rows) sx[w][f] = x[(size_t)r*64 + f];
  __syncthreads();
  if (r < rows){
    float acc = 0.f;
    for (int d = 0; d < 64; d++) acc += sx[w][d]*sth[d*64 + f];
    xt[(size_t)r*64 + f] = acc;
  }
}

__global__ __launch_bounds__(64) void k_convA(const u32* __restrict__ cHmT,
                                              const float* __restrict__ xt, int xt_per_graph,
                                              const float* __restrict__ Binv,
                                              float* __restrict__ ebuf){
  __shared__ u32 row[NW];
  int ed = blockIdx.x, g = blockIdx.y, f = threadIdx.x;
  const u32* src = cHmT + ((size_t)g*GSZ + (size_t)ed*SE)/4;
  for (int k = f; k < NW; k += 64) row[k] = src[k];
  __syncthreads();
  const float* xtg = xt + (xt_per_graph ? (size_t)g*N*H : (size_t)0);
  float acc = 0.f;
  for (int k = 0; k < NW; k++){
    u32 w = row[k];
    if (!w) continue;
    int nb = k*4;
    #pragma unroll
    for (int b = 0; b < 4; b++){
      u32 c = (w >> (b*8)) & 0xFFu;
      if (c) acc = fmaf((float)c, xtg[(size_t)(nb+b)*64 + f], acc);
    }
  }
  ebuf[((size_t)g*E + ed)*64 + f] = acc * Binv[g*E + ed];
}

__global__ __launch_bounds__(64) void k_convB(const u32* __restrict__ cHm,
                                              const float* __restrict__ ebuf,
                                              const float* __restrict__ Dinv,
                                              const float* __restrict__ bias,
                                              float* __restrict__ xout){
  __shared__ u32 row[NW];
  int n = blockIdx.x, g = blockIdx.y, f = threadIdx.x;
  const u32* src = cHm + ((size_t)g*GSZ + (size_t)n*SE)/4;
  for (int k = f; k < NW; k += 64) row[k] = src[k];
  __syncthreads();
  const float* eg = ebuf + (size_t)g*E*64;
  float acc = 0.f;
  for (int k = 0; k < NW; k++){
    u32 w = row[k];
    if (!w) continue;
    int nb = k*4;
    #pragma unroll
    for (int b = 0; b < 4; b++){
      u32 c = (w >> (b*8)) & 0xFFu;
      if (c) acc = fmaf((float)c, eg[(size_t)(nb+b)*64 + f], acc);
    }
  }
  float v = acc * Dinv[g*N + n] + bias[f];
  xout[((size_t)g*N + n)*64 + f] = leakyf(v);
}

__global__ __launch_bounds__(256) void k_bmean(const float* __restrict__ x2,
                                               float* __restrict__ bout){
  int k = blockIdx.x, tid = threadIdx.x;
  const float* a = x2 + (size_t)k*N*H;
  const float* c = x2 + (size_t)(k+1)*N*H;
  float s = 0.f;
  for (int i = tid; i < N*H; i += 256) s += c[i] - a[i];
  __shared__ float red[256];
  red[tid] = s; __syncthreads();
  for (int off = 128; off; off >>= 1){ if (tid < off) red[tid] += red[tid+off]; __syncthreads(); }
  if (tid == 0) bout[k] = red[0] / (float)(N*H);
}

__global__ __launch_bounds__(256) void k_zred(const float* __restrict__ x2,
                                              const float* __restrict__ bout,
                                              const float* __restrict__ a_param,
                                              float* __restrict__ zout){
  int k = blockIdx.x, tid = threadIdx.x;
  const float* a = x2 + (size_t)k*N*H;
  const float* c = x2 + (size_t)(k+1)*N*H;
  float bk = bout[k], ap = a_param[k];
  float s = 0.f;
  for (int i = tid; i < N*H; i += 256){
    float sub = c[i] - a[i];
    float U = 1.f/(1.f + ap*(bk - sub));
    s += (U*sub)/U;
  }
  __shared__ float red[256];
  red[tid] = s; __syncthreads();
  for (int off = 128; off; off >>= 1){ if (tid < off) red[tid] += red[tid+off]; __syncthreads(); }
  if (tid == 0) zout[k] = red[0];
}

__global__ __launch_bounds__(64) void k_wattn(const float* __restrict__ z,
                                              const float* __restrict__ w1,
                                              const float* __restrict__ w2,
                                              float* __restrict__ wa){
  __shared__ float sz[TM], sy[64], sv[TM];
  int tid = threadIdx.x;
  if (tid < TM) sz[tid] = z[tid];
  __syncthreads();
  float y = 0.f;
  for (int kk = 0; kk < TM; kk++) y += w1[tid*TM + kk]*sz[kk];
  sy[tid] = leakyf(y);
  __syncthreads();
  if (tid < TM){
    float v = 0.f;
    for (int d = 0; d < 64; d++) v += w2[tid*64 + d]*sy[d];
    sv[tid] = v;
  }
  __syncthreads();
  if (tid == 0){
    float m = sv[0];
    for (int t = 1; t < TM; t++) m = fmaxf(m, sv[t]);
    float e[TM]; float den = 0.f;
    for (int t = 0; t < TM; t++){ e[t] = expf(sv[t]-m); den += e[t]; }
    for (int t = 0; t < TM; t++) wa[t] = e[t]/den;
  }
}

__global__ __launch_bounds__(256) void k_final(const float* __restrict__ x2,
                                               const float* __restrict__ wa,
                                               const float* __restrict__ Wl,
                                               const float* __restrict__ bl,
                                               const int* __restrict__ flag,
                                               void* __restrict__ outv){
  int n = blockIdx.x*256 + threadIdx.x;
  if (n >= N) return;
  float w0 = wa[0], w2v = wa[2];
  float acc = bl[0];
  for (int h = 0; h < 64; h++){
    float xg = x2[(size_t)8*N*H + (size_t)n*64 + h];
    float s0 = x2[(size_t)1*N*H + (size_t)n*64 + h] - x2[(size_t)0*N*H + (size_t)n*64 + h];
    float s2 = x2[(size_t)3*N*H + (size_t)n*64 + h] - x2[(size_t)2*N*H + (size_t)n*64 + h];
    float xx = w0*s0 + w2v*s2;
    acc += xg*Wl[h] + xx*Wl[64 + h];
  }
  float r = leakyf(acc);
  if (*flag) ((float*)outv)[n] = r;
  else       ((__hip_bfloat16*)outv)[n] = __float2bfloat16(r);
}

extern "C" void kernel_launch(void* const* d_in, const int* in_sizes, int n_in,
                              void* d_out, int out_size, void* d_ws, size_t ws_size,
                              hipStream_t stream) {
  const int* hypT = (const int*)d_in[1];
  const int* hyp  = (const int*)d_in[2];

  char* ws = (char*)d_ws;
  float* cv  = (float*)ws;
  int* flag  = (int*)(cv + TOT_CVT);
  u32* cHm   = (u32*)(ws + (size_t)CVT_PAD*4);
  u32* cHmT  = (u32*)(ws + (size_t)CVT_PAD*4 + (size_t)NG*GSZ);
  float* fp  = (float*)(ws + (size_t)CVT_PAD*4 + (size_t)2*NG*GSZ);
  float* Dinv = fp;                 fp += NG*N;
  float* Binv = fp;                 fp += NG*E;
  float* ctx  = fp;                 fp += (size_t)N*T*H;
  float* last = fp;                 fp += (size_t)N*H;
  float* outp = fp;                 fp += (size_t)N*H;
  float* xt1  = fp;                 fp += (size_t)N*H;
  float* ebuf = fp;                 fp += (size_t)NG*E*H;
  float* x1   = fp;                 fp += (size_t)NG*N*H;
  float* xt2  = fp;                 fp += (size_t)NG*N*H;
  float* x2   = fp;                 fp += (size_t)NG*N*H;
  float* bv   = fp;                 fp += TM;
  float* zv   = fp;                 fp += TM;
  float* wa   = fp;                 fp += TM;

  const float* price  = cv + OFF_PRICE;
  const float* Wih    = cv + OFF_WIH;
  const float* Whh    = cv + OFF_WHH;
  const float* bih    = cv + OFF_BIH;
  const float* bhh    = cv + OFF_BHH;
  const float* Win    = cv + OFF_WIN;
  const float* Wout   = cv + OFF_WOUT;
  const float* ae     = cv + OFF_AE;
  const float* ab     = cv + OFF_AB;
  const float* theta1 = cv + OFF_TH1;
  const float* bias1  = cv + OFF_B1;
  const float* theta2 = cv + OFF_TH2;
  const float* bias2  = cv + OFF_B2;
  const float* w1     = cv + OFF_W1;
  const float* w2     = cv + OFF_W2;
  const float* a_par  = cv + OFF_APAR;
  const float* Wl     = cv + OFF_WL;
  const float* bl     = cv + OFF_BL;

  hipMemsetAsync(cHm, 0, (size_t)2*NG*GSZ, stream);

  k_detect<<<1, 64, 0, stream>>>((const unsigned short*)d_in[3], flag);
  CvtPtrs ps;
  ps.p[0]=d_in[0];  ps.p[1]=d_in[3];  ps.p[2]=d_in[4];  ps.p[3]=d_in[5];
  ps.p[4]=d_in[6];  ps.p[5]=d_in[7];  ps.p[6]=d_in[8];  ps.p[7]=d_in[9];
  ps.p[8]=d_in[10]; ps.p[9]=d_in[11]; ps.p[10]=d_in[12]; ps.p[11]=d_in[13];
  ps.p[12]=d_in[14]; ps.p[13]=d_in[15]; ps.p[14]=d_in[16]; ps.p[15]=d_in[17];
  ps.p[16]=d_in[18]; ps.p[17]=d_in[19];
  k_cvt<<<(TOT_CVT+255)/256, 256, 0, stream>>>(flag, ps, cv);

  k_build<<<dim3((NNZ+255)/256, NG), 256, 0, stream>>>(hypT, hyp, cHm, cHmT);
  k_deg  <<<dim3(N, NG, 2), 64, 0, stream>>>(cHm, cHmT, Dinv, Binv);
  k_gru  <<<N, 64, 0, stream>>>(price, Wih, Whh, bih, bhh, ctx, last);
  k_attn <<<N, 64, 0, stream>>>(ctx, last, Win, Wout, ae, ab, outp);

  k_xtheta<<<(N+3)/4, 256, 0, stream>>>(outp, theta1, xt1, N);
  k_convA <<<dim3(E, NG), 64, 0, stream>>>(cHmT, xt1, 0, Binv, ebuf);
  k_convB <<<dim3(N, NG), 64, 0, stream>>>(cHm, ebuf, Dinv, bias1, x1);

  k_xtheta<<<(NG*N+3)/4, 256, 0, stream>>>(x1, theta2, xt2, NG*N);
  k_convA <<<dim3(E, NG), 64, 0, stream>>>(cHmT, xt2, 1, Binv, ebuf);
  k_convB <<<dim3(N, NG), 64, 0, stream>>>(cHm, ebuf, Dinv, bias2, x2);

  k_bmean<<<TM, 256, 0, stream>>>(x2, bv);
  k_zred <<<TM, 256, 0, stream>>>(x2, bv, a_par, zv);
  k_wattn<<<1, 64, 0, stream>>>(zv, w1, w2, wa);
  k_final<<<(N+255)/256, 256, 0, stream>>>(x2, wa, Wl, bl, flag, d_out);
}